// Round 3
// baseline (353.948 us; speedup 1.0000x reference)
//
#include <hip/hip_runtime.h>

// LinearAttend: q,k,v (4,8,64,8192) fp32.
//   qs = softmax(q, axis=d) * d^-0.5 ; ks = softmax(k, axis=s)
//   C[i][j] = sum_s ks[i,s] v[j,s]   (64x64 per head)
//   out[j][s] = sum_i C[i][j] qs[i,s]
// exp() without max-subtraction is safe in fp32 for N(0,1) inputs.
// Pipeline: ctx_kernel (per-chunk partial C' + rowsum, no atomics) ->
//           reduce_kernel (sum chunks, fold 0.125/rowsum -> Cn) ->
//           out_kernel (LDS-tiled GEMM: Out = Cn^T * softmax_col(exp(q))).

constexpr int D = 64;
constexpr int S = 8192;
constexpr int HEADS = 32;      // b*n = 4*8
constexpr int TS = 64;         // staged s-tile width (ctx)
constexpr int LSTR = 68;       // ctx LDS row stride (conflict-free 8x8 reads)
constexpr int SC = 256;        // s-columns per out block

// ---------------------------------------------------------------- ctx ----
__global__ __launch_bounds__(256) void ctx_kernel(
    const float* __restrict__ K, const float* __restrict__ V,
    float* __restrict__ Cpart,   // [HEADS][NS][64*64] unnormalized partials
    float* __restrict__ Rpart)   // [HEADS][NS][64]    rowsum partials
{
    __shared__ float eK[D][LSTR];
    __shared__ float vV[D][LSTR];
    const int h = blockIdx.x, c = blockIdx.y;
    const int NSr = gridDim.y;
    const int chunk = S / NSr;
    const int t = threadIdx.x;
    const int lane = t & 63, wave = t >> 6;
    const int li = lane & 7;        // owns C rows  li, li+8, ..., li+56
    const int lj = lane >> 3;       // owns C cols  lj, lj+8, ..., lj+56

    const float* Kh = K + (size_t)h * D * S;
    const float* Vh = V + (size_t)h * D * S;

    float acc[8][8];
#pragma unroll
    for (int a = 0; a < 8; ++a)
#pragma unroll
        for (int b = 0; b < 8; ++b) acc[a][b] = 0.f;
    float rs[4] = {0.f, 0.f, 0.f, 0.f};

    const int s_begin = c * chunk, s_end = s_begin + chunk;
    for (int s0 = s_begin; s0 < s_end; s0 += TS) {
        // ---- stage: flat4 = t + 256m covers 64x16 float4s, coalesced ----
#pragma unroll
        for (int m = 0; m < 4; ++m) {
            const int flat4 = t + 256 * m;
            const int row = flat4 >> 4;
            const int col = (flat4 & 15) * 4;
            float4 kv = *(const float4*)(Kh + (size_t)row * S + s0 + col);
            float4 vv = *(const float4*)(Vh + (size_t)row * S + s0 + col);
            float4 ev;
            ev.x = __expf(kv.x); ev.y = __expf(kv.y);
            ev.z = __expf(kv.z); ev.w = __expf(kv.w);
            rs[m] += (ev.x + ev.y) + (ev.z + ev.w);
            *(float4*)&eK[row][col] = ev;
            *(float4*)&vV[row][col] = vv;
        }
        __syncthreads();
        // ---- compute: wave w owns s in [16w, 16w+16) of this tile ----
#pragma unroll
        for (int ss = 0; ss < 16; ss += 4) {
            const int s = wave * 16 + ss;
            float4 vv[8];
#pragma unroll
            for (int b = 0; b < 8; ++b)
                vv[b] = *(const float4*)&vV[lj + 8 * b][s];
#pragma unroll
            for (int a = 0; a < 8; ++a) {
                float4 ek = *(const float4*)&eK[li + 8 * a][s];
#pragma unroll
                for (int b = 0; b < 8; ++b)
                    acc[a][b] += ek.x * vv[b].x + ek.y * vv[b].y
                               + ek.z * vv[b].z + ek.w * vv[b].w;
            }
        }
        __syncthreads();
    }

    // ---- rowsum partials into LDS (reuse vV, stride 17) ----
    float* rbuf = &vV[0][0];
#pragma unroll
    for (int m = 0; m < 4; ++m)
        rbuf[((t >> 4) + 16 * m) * 17 + (t & 15)] = rs[m];

    // ---- cross-wave C merge in LDS (reuse eK, stride-68 layout) ----
    float* Cbuf = &eK[0][0];
    for (int w = 0; w < 4; ++w) {
        if (wave == w) {
#pragma unroll
            for (int a = 0; a < 8; ++a)
#pragma unroll
                for (int b = 0; b < 8; ++b) {
                    const int idx = (li + 8 * a) * LSTR + (lj + 8 * b);
                    const float v0 = (w == 0) ? acc[a][b] : Cbuf[idx] + acc[a][b];
                    Cbuf[idx] = v0;
                }
        }
        __syncthreads();
    }

    if (t < D) {
        float ssum = 0.f;
#pragma unroll
        for (int q = 0; q < 16; ++q) ssum += rbuf[t * 17 + q];
        Rpart[((size_t)h * NSr + c) * D + t] = ssum;
    }
    const size_t pbase = ((size_t)h * NSr + c) * (size_t)(D * D);
#pragma unroll
    for (int m = 0; m < 16; ++m) {
        const int flat = t + 256 * m;
        Cpart[pbase + flat] = Cbuf[(flat >> 6) * LSTR + (flat & 63)];
    }
}

// ------------------------------------------------------------- reduce ----
__global__ __launch_bounds__(256) void reduce_kernel(
    const float* __restrict__ Cpart, const float* __restrict__ Rpart,
    float* __restrict__ Cn, int NSr)  // Cn: [HEADS][64*64], normalized*0.125
{
    __shared__ float invr[D];
    const int h = blockIdx.x, p = blockIdx.y, t = threadIdx.x;

    if (t < D) {
        float s = 0.f;
        for (int c = 0; c < NSr; ++c)
            s += Rpart[((size_t)h * NSr + c) * D + t];
        invr[t] = 0.125f / s;
    }
    __syncthreads();

#pragma unroll
    for (int m = 0; m < 4; ++m) {
        const int flat = p * 1024 + t + 256 * m;
        float s = 0.f;
        for (int c = 0; c < NSr; ++c)
            s += Cpart[((size_t)h * NSr + c) * (size_t)(D * D) + flat];
        Cn[(size_t)h * (D * D) + flat] = s * invr[flat >> 6];
    }
}

// ---------------------------------------------------------------- out ----
// Out[j][s] = sum_i Cn[i][j] * E[i][s] / colsum(E)[s],  E = exp(q).
// LDS: E 64x256 (64KB) + Cs 64x64 (16KB) = 80KB -> 2 blocks/CU.
__global__ __launch_bounds__(256) void out_kernel(
    const float* __restrict__ Q, const float* __restrict__ Cn,
    float* __restrict__ Out)
{
    __shared__ float E[D][SC];
    __shared__ float Cs[D][D];
    const int h = blockIdx.x, cb = blockIdx.y, t = threadIdx.x;

    const float* Qh = Q + (size_t)h * D * S + (size_t)cb * SC;

    // ---- stage E = exp(q tile), coalesced ----
#pragma unroll
    for (int m = 0; m < 16; ++m) {
        const int flat4 = t + 256 * m;     // 4096 float4s = 64 rows x 64
        const int row = flat4 >> 6;
        const int c4 = (flat4 & 63) * 4;
        float4 qv = *(const float4*)(Qh + (size_t)row * S + c4);
        float4 ev;
        ev.x = __expf(qv.x); ev.y = __expf(qv.y);
        ev.z = __expf(qv.z); ev.w = __expf(qv.w);
        *(float4*)&E[row][c4] = ev;
    }
    // ---- stage Cs (16 KB, L2-resident) ----
#pragma unroll
    for (int m = 0; m < 4; ++m) {
        const int flat4 = t + 256 * m;     // 1024 float4s = 64 rows x 16
        const int row = flat4 >> 4;
        const int c4 = (flat4 & 15) * 4;
        *(float4*)&Cs[row][c4] = *(const float4*)(Cn + (size_t)h * D * D + flat4 * 4);
    }
    __syncthreads();

    // ---- column softmax denominators; normalize E in place ----
    {
        float s = 0.f;
#pragma unroll
        for (int i = 0; i < D; ++i) s += E[i][t];   // lane-consecutive
        const float inv = 1.0f / s;
#pragma unroll
        for (int i = 0; i < D; ++i) E[i][t] *= inv;
    }
    __syncthreads();

    // ---- GEMM: thread = 8 j x 8 s ----
    const int tj = t >> 5;       // j block: 8*tj .. 8*tj+7
    const int ts = t & 31;       // s: ts + 32*m, m = 0..7
    float acc[8][8];
#pragma unroll
    for (int a = 0; a < 8; ++a)
#pragma unroll
        for (int b = 0; b < 8; ++b) acc[a][b] = 0.f;

#pragma unroll 8
    for (int i = 0; i < D; ++i) {
        const float4 c0 = *(const float4*)&Cs[i][8 * tj];
        const float4 c1 = *(const float4*)&Cs[i][8 * tj + 4];
        const float cj[8] = {c0.x, c0.y, c0.z, c0.w, c1.x, c1.y, c1.z, c1.w};
        float e[8];
#pragma unroll
        for (int m = 0; m < 8; ++m) e[m] = E[i][ts + 32 * m];
#pragma unroll
        for (int a = 0; a < 8; ++a)
#pragma unroll
            for (int m = 0; m < 8; ++m)
                acc[a][m] += cj[a] * e[m];
    }

    // ---- store: per (j, m) lanes are s-consecutive ----
    float* Oh = Out + (size_t)h * D * S + (size_t)cb * SC;
#pragma unroll
    for (int a = 0; a < 8; ++a) {
        const int j = 8 * tj + a;
#pragma unroll
        for (int m = 0; m < 8; ++m)
            Oh[(size_t)j * S + ts + 32 * m] = acc[a][m];
    }
}

extern "C" void kernel_launch(void* const* d_in, const int* in_sizes, int n_in,
                              void* d_out, int out_size, void* d_ws, size_t ws_size,
                              hipStream_t stream) {
    const float* q = (const float*)d_in[0];
    const float* k = (const float*)d_in[1];
    const float* v = (const float*)d_in[2];
    float* out = (float*)d_out;

    // NS=32 needs 32*32*(4096+64)*4 + 32*4096*4 bytes of ws; fall back if small.
    const size_t need32 = (size_t)HEADS * 32 * (D * D + D) * 4 + (size_t)HEADS * D * D * 4;
    const int NS = (ws_size >= need32) ? 32 : 16;

    float* Cpart = (float*)d_ws;                               // HEADS*NS*4096
    float* Rpart = Cpart + (size_t)HEADS * NS * D * D;         // HEADS*NS*64
    float* Cn    = Rpart + (size_t)HEADS * NS * D;             // HEADS*4096

    ctx_kernel<<<dim3(HEADS, NS), 256, 0, stream>>>(k, v, Cpart, Rpart);
    reduce_kernel<<<dim3(HEADS, 4), 256, 0, stream>>>(Cpart, Rpart, Cn, NS);
    out_kernel<<<dim3(HEADS, S / SC), 256, 0, stream>>>(q, Cn, out);
}

// Round 4
// 286.248 us; speedup vs baseline: 1.2365x; 1.2365x over previous
//
#include <hip/hip_runtime.h>

// LinearAttend: q,k,v (4,8,64,8192) fp32.
//   qs = softmax(q, axis=d) * d^-0.5 ; ks = softmax(k, axis=s)
//   C[i][j] = sum_s ks[i,s] v[j,s]   (64x64 per head)
//   out[j][s] = sum_i C[i][j] qs[i,s]
// exp() without max-subtraction is safe in fp32 for N(0,1) inputs.
// Pipeline: ctx_kernel (per-chunk partial C' + rowsum, prefetched staging) ->
//           reduce_kernel (sum chunks, fold 0.125/rowsum -> Cn) ->
//           out_kernel (LDS-free: wave-uniform Cn via s_load, q in regs).

constexpr int D = 64;
constexpr int S = 8192;
constexpr int HEADS = 32;      // b*n = 4*8
constexpr int NS = 16;         // s-chunks for ctx partials (proven sweet spot)
constexpr int CHUNK = S / NS;  // 512
constexpr int TS = 64;         // staged s-tile width (ctx)
constexpr int LSTR = 68;       // ctx LDS row stride (conflict-free 8x8 reads)

// ---------------------------------------------------------------- ctx ----
__global__ __launch_bounds__(256) void ctx_kernel(
    const float* __restrict__ K, const float* __restrict__ V,
    float* __restrict__ Cpart,   // [HEADS][NS][64*64] unnormalized partials
    float* __restrict__ Rpart)   // [HEADS][NS][64]    rowsum partials
{
    __shared__ float eK[D][LSTR];
    __shared__ float vV[D][LSTR];
    const int h = blockIdx.x, c = blockIdx.y;
    const int t = threadIdx.x;
    const int lane = t & 63, wave = t >> 6;
    const int li = lane & 7;        // owns C rows  li, li+8, ..., li+56
    const int lj = lane >> 3;       // owns C cols  lj, lj+8, ..., lj+56

    const float* Kh = K + (size_t)h * D * S;
    const float* Vh = V + (size_t)h * D * S;

    // staging map: thread covers rows r0+16m, 16B chunk c0, m=0..3
    const int r0 = t >> 4;
    const int c0 = (t & 15) * 4;
    const float* Kp = Kh + (size_t)r0 * S + c0;
    const float* Vp = Vh + (size_t)r0 * S + c0;

    float acc[8][8];
#pragma unroll
    for (int a = 0; a < 8; ++a)
#pragma unroll
        for (int b = 0; b < 8; ++b) acc[a][b] = 0.f;
    float rs[4] = {0.f, 0.f, 0.f, 0.f};

    const int s_begin = c * CHUNK;

    // ---- prologue: prefetch tile 0 into registers ----
    float4 pk[4], pv[4];
#pragma unroll
    for (int m = 0; m < 4; ++m) {
        pk[m] = *(const float4*)(Kp + (size_t)(16 * m) * S + s_begin);
        pv[m] = *(const float4*)(Vp + (size_t)(16 * m) * S + s_begin);
    }

    for (int tile = 0; tile < CHUNK / TS; ++tile) {
        // ---- drain regs -> LDS (exp applied to K) ----
#pragma unroll
        for (int m = 0; m < 4; ++m) {
            float4 ev;
            ev.x = __expf(pk[m].x); ev.y = __expf(pk[m].y);
            ev.z = __expf(pk[m].z); ev.w = __expf(pk[m].w);
            rs[m] += (ev.x + ev.y) + (ev.z + ev.w);
            *(float4*)&eK[r0 + 16 * m][c0] = ev;
            *(float4*)&vV[r0 + 16 * m][c0] = pv[m];
        }
        __syncthreads();

        // ---- issue next tile's loads; they fly during compute ----
        if (tile + 1 < CHUNK / TS) {
            const int sn = s_begin + (tile + 1) * TS;
#pragma unroll
            for (int m = 0; m < 4; ++m) {
                pk[m] = *(const float4*)(Kp + (size_t)(16 * m) * S + sn);
                pv[m] = *(const float4*)(Vp + (size_t)(16 * m) * S + sn);
            }
        }

        // ---- compute: wave w owns s in [16w, 16w+16) of this tile ----
#pragma unroll
        for (int ss = 0; ss < 16; ss += 4) {
            const int s = wave * 16 + ss;
            float4 vv[8];
#pragma unroll
            for (int b = 0; b < 8; ++b)
                vv[b] = *(const float4*)&vV[lj + 8 * b][s];
#pragma unroll
            for (int a = 0; a < 8; ++a) {
                float4 ek = *(const float4*)&eK[li + 8 * a][s];
#pragma unroll
                for (int b = 0; b < 8; ++b)
                    acc[a][b] += ek.x * vv[b].x + ek.y * vv[b].y
                               + ek.z * vv[b].z + ek.w * vv[b].w;
            }
        }
        __syncthreads();
    }

    // ---- rowsum partials into LDS (reuse vV) ----
    float* rbuf = &vV[0][0];
#pragma unroll
    for (int m = 0; m < 4; ++m)
        rbuf[((t >> 4) + 16 * m) * 17 + (t & 15)] = rs[m];

    // ---- cross-wave C merge in LDS (reuse eK, stride-68 layout) ----
    float* Cbuf = &eK[0][0];
    for (int w = 0; w < 4; ++w) {
        if (wave == w) {
#pragma unroll
            for (int a = 0; a < 8; ++a)
#pragma unroll
                for (int b = 0; b < 8; ++b) {
                    const int idx = (li + 8 * a) * LSTR + (lj + 8 * b);
                    const float v0 = (w == 0) ? acc[a][b] : Cbuf[idx] + acc[a][b];
                    Cbuf[idx] = v0;
                }
        }
        __syncthreads();
    }

    if (t < D) {
        float ssum = 0.f;
#pragma unroll
        for (int q = 0; q < 16; ++q) ssum += rbuf[t * 17 + q];
        Rpart[((size_t)h * NS + c) * D + t] = ssum;
    }
    const size_t pbase = ((size_t)h * NS + c) * (size_t)(D * D);
#pragma unroll
    for (int m = 0; m < 16; ++m) {
        const int flat = t + 256 * m;
        Cpart[pbase + flat] = Cbuf[(flat >> 6) * LSTR + (flat & 63)];
    }
}

// ------------------------------------------------------------- reduce ----
__global__ __launch_bounds__(256) void reduce_kernel(
    const float* __restrict__ Cpart, const float* __restrict__ Rpart,
    float* __restrict__ Cn)          // [HEADS][64*64], normalized*0.125
{
    __shared__ float invr[D];
    const int h = blockIdx.x, p = blockIdx.y, t = threadIdx.x;

    if (t < D) {
        float s = 0.f;
#pragma unroll
        for (int c = 0; c < NS; ++c)
            s += Rpart[((size_t)h * NS + c) * D + t];
        invr[t] = 0.125f / s;
    }
    __syncthreads();

    const int flat = p * 256 + t;
    float s = 0.f;
#pragma unroll
    for (int c = 0; c < NS; ++c)
        s += Cpart[((size_t)h * NS + c) * (size_t)(D * D) + flat];
    Cn[(size_t)h * (D * D) + flat] = s * invr[flat >> 6];
}

// ---------------------------------------------------------------- out ----
// Out[j][s] = (sum_i Cn[i][j] * e[i][s]) / (sum_i e[i][s]),  e = exp(q).
// Wave w owns j in [16w, 16w+16): Cn addresses are wave-uniform -> s_load.
// Lane owns 4 consecutive s. No LDS at all; q read once, straight to regs.
__global__ __launch_bounds__(256) void out_kernel(
    const float* __restrict__ Q, const float* __restrict__ Cn,
    float* __restrict__ Out)
{
    const int h = blockIdx.x, cb = blockIdx.y, t = threadIdx.x;
    const int lane = t & 63;
    const int w = __builtin_amdgcn_readfirstlane(t >> 6);  // force SGPR
    const int s = cb * 256 + 4 * lane;

    const float* Qh = Q + (size_t)h * D * S + s;
    const float* Ch = Cn + (size_t)h * D * D + 16 * w;     // SGPR base

    float4 acc[16];
#pragma unroll
    for (int jj = 0; jj < 16; ++jj) acc[jj] = make_float4(0.f, 0.f, 0.f, 0.f);
    float4 esum = make_float4(0.f, 0.f, 0.f, 0.f);

#pragma unroll 4
    for (int i = 0; i < D; ++i) {
        const float4 qv = *(const float4*)(Qh + (size_t)i * S);  // 1KB/wave
        float4 e;
        e.x = __expf(qv.x); e.y = __expf(qv.y);
        e.z = __expf(qv.z); e.w = __expf(qv.w);
        esum.x += e.x; esum.y += e.y; esum.z += e.z; esum.w += e.w;
#pragma unroll
        for (int jj = 0; jj < 16; ++jj) {
            const float cv = Ch[(size_t)i * D + jj];  // uniform -> s_load
            acc[jj].x += cv * e.x;
            acc[jj].y += cv * e.y;
            acc[jj].z += cv * e.z;
            acc[jj].w += cv * e.w;
        }
    }

    const float ix = 1.f / esum.x, iy = 1.f / esum.y;
    const float iz = 1.f / esum.z, iw = 1.f / esum.w;

    float* Oh = Out + (size_t)h * D * S + (size_t)(16 * w) * S + s;
#pragma unroll
    for (int jj = 0; jj < 16; ++jj) {
        float4 r;
        r.x = acc[jj].x * ix; r.y = acc[jj].y * iy;
        r.z = acc[jj].z * iz; r.w = acc[jj].w * iw;
        *(float4*)(Oh + (size_t)jj * S) = r;        // 1KB/wave coalesced
    }
}

extern "C" void kernel_launch(void* const* d_in, const int* in_sizes, int n_in,
                              void* d_out, int out_size, void* d_ws, size_t ws_size,
                              hipStream_t stream) {
    const float* q = (const float*)d_in[0];
    const float* k = (const float*)d_in[1];
    const float* v = (const float*)d_in[2];
    float* out = (float*)d_out;

    float* Cpart = (float*)d_ws;                               // 8 MB
    float* Rpart = Cpart + (size_t)HEADS * NS * D * D;         // 128 KB
    float* Cn    = Rpart + (size_t)HEADS * NS * D;             // 512 KB

    ctx_kernel<<<dim3(HEADS, NS), 256, 0, stream>>>(k, v, Cpart, Rpart);
    reduce_kernel<<<dim3(HEADS, NS), 256, 0, stream>>>(Cpart, Rpart, Cn);
    out_kernel<<<dim3(HEADS, S / 256), 256, 0, stream>>>(q, Cn, out);
}

// Round 5
// 267.196 us; speedup vs baseline: 1.3247x; 1.0713x over previous
//
#include <hip/hip_runtime.h>

// LinearAttend: q,k,v (4,8,64,8192) fp32.
//   out[j][s] = sum_i (C'[i][j]/rowsum[i]) * 0.125 * exp(q[i][s])/colsum[s]
//   C'[i][j]  = sum_s exp(k[i][s]) * v[j][s]
// Both GEMMs via split-bf16 MFMA (x = hi + lo, 3 MFMAs: AhBh + AhBl + AlBh),
// error ~2^-18 relative. mfma_f32_16x16x32_bf16 frags are 8 contiguous
// floats/lane -> load straight from global, no LDS in any inner loop.

typedef __attribute__((ext_vector_type(8))) short bf16x8;
typedef __attribute__((ext_vector_type(4))) float floatx4;

constexpr int D = 64, S = 8192, HEADS = 32;
constexpr int NC = 32;               // ctx partial chunks per head
constexpr int CHUNK = S / NC;        // 256 s per ctx block

__device__ __forceinline__ short bf16_rn(float x) {
    unsigned u = __builtin_bit_cast(unsigned, x);
    return (short)((u + 0x8000u) >> 16);
}
__device__ __forceinline__ float bf16_f(short h) {
    unsigned u = ((unsigned)(unsigned short)h) << 16;
    return __builtin_bit_cast(float, u);
}
__device__ __forceinline__ void split8(const float* x, bf16x8& hi, bf16x8& lo) {
#pragma unroll
    for (int e = 0; e < 8; ++e) {
        short h = bf16_rn(x[e]);
        hi[e] = h;
        lo[e] = bf16_rn(x[e] - bf16_f(h));
    }
}

// ---------------------------------------------------------------- ctx ----
// Grid (32 heads, 32 chunks) x 256. Wave w covers 64 s (2 iters of K=32).
// Per iter a lane loads A = expK[mt*16+m][s0+quad*8..+7] and
// B = V[nt*16+m][same s] (8 contiguous floats each), 16 MFMA tiles.
__global__ __launch_bounds__(256) void ctx_kernel(
    const float* __restrict__ K, const float* __restrict__ V,
    float* __restrict__ Cpart,   // [h][c][tile][reg][lane]  (16 KB per block)
    float* __restrict__ Rpart)   // [h][c][64] rowsum partials
{
    __shared__ float buf[16 * 4 * 64];   // merge buffer [tile][reg][lane]
    __shared__ float rbuf[64];
    const int h = blockIdx.x, c = blockIdx.y;
    const int wave = threadIdx.x >> 6, lane = threadIdx.x & 63;
    const int m = lane & 15, quad = lane >> 4;

    const float* Kb = K + (size_t)h * D * S;
    const float* Vb = V + (size_t)h * D * S;

    floatx4 acc[4][4];
#pragma unroll
    for (int a = 0; a < 4; ++a)
#pragma unroll
        for (int b = 0; b < 4; ++b) acc[a][b] = (floatx4){0.f, 0.f, 0.f, 0.f};
    float rs[4] = {0.f, 0.f, 0.f, 0.f};

    float kraw[4][8], vraw[4][8];
    const int sw = c * CHUNK + wave * 64 + quad * 8;

#pragma unroll
    for (int mt = 0; mt < 4; ++mt) {          // prefetch iter 0
        const float* pk = Kb + (size_t)(mt * 16 + m) * S + sw;
        const float* pv = Vb + (size_t)(mt * 16 + m) * S + sw;
        *(float4*)&kraw[mt][0] = *(const float4*)pk;
        *(float4*)&kraw[mt][4] = *(const float4*)(pk + 4);
        *(float4*)&vraw[mt][0] = *(const float4*)pv;
        *(float4*)&vraw[mt][4] = *(const float4*)(pv + 4);
    }

    for (int it = 0; it < 2; ++it) {
        bf16x8 ah[4], al[4], bh[4], bl[4];
#pragma unroll
        for (int mt = 0; mt < 4; ++mt) {
            float ex[8];
#pragma unroll
            for (int e = 0; e < 8; ++e) {
                ex[e] = __expf(kraw[mt][e]);
                rs[mt] += ex[e];
            }
            split8(ex, ah[mt], al[mt]);
            split8(vraw[mt], bh[mt], bl[mt]);
        }
        if (it == 0) {                        // prefetch iter 1 during MFMAs
#pragma unroll
            for (int mt = 0; mt < 4; ++mt) {
                const float* pk = Kb + (size_t)(mt * 16 + m) * S + sw + 32;
                const float* pv = Vb + (size_t)(mt * 16 + m) * S + sw + 32;
                *(float4*)&kraw[mt][0] = *(const float4*)pk;
                *(float4*)&kraw[mt][4] = *(const float4*)(pk + 4);
                *(float4*)&vraw[mt][0] = *(const float4*)pv;
                *(float4*)&vraw[mt][4] = *(const float4*)(pv + 4);
            }
        }
#pragma unroll
        for (int mt = 0; mt < 4; ++mt)
#pragma unroll
            for (int nt = 0; nt < 4; ++nt) {
                acc[mt][nt] = __builtin_amdgcn_mfma_f32_16x16x32_bf16(
                    ah[mt], bh[nt], acc[mt][nt], 0, 0, 0);
                acc[mt][nt] = __builtin_amdgcn_mfma_f32_16x16x32_bf16(
                    ah[mt], bl[nt], acc[mt][nt], 0, 0, 0);
                acc[mt][nt] = __builtin_amdgcn_mfma_f32_16x16x32_bf16(
                    al[mt], bh[nt], acc[mt][nt], 0, 0, 0);
            }
    }

    // rowsum: butterfly over quad bits -> row totals at all lanes
#pragma unroll
    for (int mt = 0; mt < 4; ++mt) {
        float v0 = rs[mt];
        v0 += __shfl_xor(v0, 16, 64);
        v0 += __shfl_xor(v0, 32, 64);
        rs[mt] = v0;
    }

    // cross-wave merge (once per kernel)
    for (int w = 0; w < 4; ++w) {
        if (wave == w) {
#pragma unroll
            for (int mt = 0; mt < 4; ++mt) {
                if (lane < 16)
                    rbuf[mt * 16 + lane] =
                        (w == 0) ? rs[mt] : rbuf[mt * 16 + lane] + rs[mt];
#pragma unroll
                for (int nt = 0; nt < 4; ++nt)
#pragma unroll
                    for (int r = 0; r < 4; ++r) {
                        const int idx = ((mt * 4 + nt) * 4 + r) * 64 + lane;
                        buf[idx] = (w == 0) ? acc[mt][nt][r]
                                            : buf[idx] + acc[mt][nt][r];
                    }
            }
        }
        __syncthreads();
    }

    const size_t pbase = ((size_t)h * NC + c) * 4096;
    for (int idx = threadIdx.x; idx < 4096; idx += 256)
        Cpart[pbase + idx] = buf[idx];
    if (threadIdx.x < 64)
        Rpart[((size_t)h * NC + c) * 64 + threadIdx.x] = rbuf[threadIdx.x];
}

// ------------------------------------------------------------- reduce ----
// Sum 32 chunks; element (tile,reg,lane): i = mt*16 + (lane>>4)*4 + reg,
// j = nt*16 + (lane&15). Write CnT[j][i] = sum * 0.125 / rowsum[i].
__global__ __launch_bounds__(256) void reduce_kernel(
    const float* __restrict__ Cpart, const float* __restrict__ Rpart,
    float* __restrict__ CnT)
{
    __shared__ float invr[D];
    const int h = blockIdx.x, t = threadIdx.x;

    if (t < D) {
        float s = 0.f;
#pragma unroll
        for (int c = 0; c < NC; ++c)
            s += Rpart[((size_t)h * NC + c) * 64 + t];
        invr[t] = 0.125f / s;
    }
    __syncthreads();

    for (int idx = t; idx < 4096; idx += 256) {
        float s = 0.f;
#pragma unroll
        for (int c = 0; c < NC; ++c)
            s += Cpart[((size_t)h * NC + c) * 4096 + idx];
        const int tile = idx >> 8, reg = (idx >> 6) & 3, lane = idx & 63;
        const int mt = tile >> 2, nt = tile & 3;
        const int i = mt * 16 + ((lane >> 4) << 2) + reg;
        const int j = nt * 16 + (lane & 15);
        CnT[(size_t)h * 4096 + j * 64 + i] = s * invr[i];
    }
}

// ---------------------------------------------------------------- out ----
// Grid (32 heads, 16) x 256. Wave covers 128 s (8 iters of 16 s).
// A = CnT rows (preloaded/split once), B = exp(q) columns; colsum via
// quad butterfly; divide at epilogue. No LDS.
__global__ __launch_bounds__(256) void out_kernel(
    const float* __restrict__ Q, const float* __restrict__ CnT,
    float* __restrict__ Out)
{
    const int h = blockIdx.x;
    const int wave = threadIdx.x >> 6, lane = threadIdx.x & 63;
    const int m = lane & 15, quad = lane >> 4;
    const int sbase = (blockIdx.y * 4 + wave) * 128;

    bf16x8 Ah[4][2], Al[4][2];
    const float* Cb = CnT + (size_t)h * 4096;
#pragma unroll
    for (int jt = 0; jt < 4; ++jt)
#pragma unroll
        for (int kk = 0; kk < 2; ++kk) {
            float a[8];
            const float* p = Cb + (jt * 16 + m) * 64 + kk * 32 + quad * 8;
            *(float4*)&a[0] = *(const float4*)p;
            *(float4*)&a[4] = *(const float4*)(p + 4);
            split8(a, Ah[jt][kk], Al[jt][kk]);
        }

    const float* Qb = Q + (size_t)h * D * S;
    float* Ob = Out + (size_t)h * D * S;

    for (int it = 0; it < 8; ++it) {
        const int scol = sbase + it * 16 + m;
        float e[16];
        float cs = 0.f;
#pragma unroll
        for (int kk = 0; kk < 2; ++kk)
#pragma unroll
            for (int j2 = 0; j2 < 8; ++j2) {
                const float qv = Qb[(size_t)(kk * 32 + quad * 8 + j2) * S + scol];
                const float ev = __expf(qv);
                e[kk * 8 + j2] = ev;
                cs += ev;
            }
        cs += __shfl_xor(cs, 16, 64);
        cs += __shfl_xor(cs, 32, 64);
        const float inv = 1.0f / cs;

        bf16x8 Bh[2], Bl[2];
        split8(&e[0], Bh[0], Bl[0]);
        split8(&e[8], Bh[1], Bl[1]);

#pragma unroll
        for (int jt = 0; jt < 4; ++jt) {
            floatx4 a = (floatx4){0.f, 0.f, 0.f, 0.f};
#pragma unroll
            for (int kk = 0; kk < 2; ++kk) {
                a = __builtin_amdgcn_mfma_f32_16x16x32_bf16(Ah[jt][kk], Bh[kk], a, 0, 0, 0);
                a = __builtin_amdgcn_mfma_f32_16x16x32_bf16(Ah[jt][kk], Bl[kk], a, 0, 0, 0);
                a = __builtin_amdgcn_mfma_f32_16x16x32_bf16(Al[jt][kk], Bh[kk], a, 0, 0, 0);
            }
#pragma unroll
            for (int r = 0; r < 4; ++r)
                Ob[(size_t)(jt * 16 + quad * 4 + r) * S + scol] = a[r] * inv;
        }
    }
}

extern "C" void kernel_launch(void* const* d_in, const int* in_sizes, int n_in,
                              void* d_out, int out_size, void* d_ws, size_t ws_size,
                              hipStream_t stream) {
    const float* q = (const float*)d_in[0];
    const float* k = (const float*)d_in[1];
    const float* v = (const float*)d_in[2];
    float* out = (float*)d_out;

    float* Cpart = (float*)d_ws;                           // 32*32*4096*4 = 16.78 MB
    float* Rpart = Cpart + (size_t)HEADS * NC * 4096;      // 256 KB
    float* CnT   = Rpart + (size_t)HEADS * NC * 64;        // 512 KB

    ctx_kernel<<<dim3(HEADS, NC), 256, 0, stream>>>(k, v, Cpart, Rpart);
    reduce_kernel<<<dim3(HEADS), 256, 0, stream>>>(Cpart, Rpart, CnT);
    out_kernel<<<dim3(HEADS, 16), 256, 0, stream>>>(q, CnT, out);
}